// Round 4
// baseline (538.936 us; speedup 1.0000x reference)
//
#include <hip/hip_runtime.h>
#include <hip/hip_bf16.h>
#include <cstdint>

#define NBATCH 2
#define NSEQ   512
#define DHID   100

typedef __bf16 bf16x8 __attribute__((ext_vector_type(8)));
typedef __bf16 bf16x4 __attribute__((ext_vector_type(4)));
typedef float  f32x4  __attribute__((ext_vector_type(4)));
typedef short  short4v __attribute__((ext_vector_type(4)));

// 16x16x16 bf16 MFMA: B-frag layout (lane g,l16 -> B[g*4+j][l16]) matches the
// 16x16 C/D layout, so GEMM2's h operand comes straight from GEMM1's accumulator.
static __device__ __forceinline__ f32x4 mfma16(bf16x4 a, bf16x4 b, f32x4 c) {
#if __has_builtin(__builtin_amdgcn_mfma_f32_16x16x16bf16_1k)
    return __builtin_amdgcn_mfma_f32_16x16x16bf16_1k(
        __builtin_bit_cast(short4v, a), __builtin_bit_cast(short4v, b), c, 0, 0, 0);
#else
    f32x4 d = c;
    asm("v_mfma_f32_16x16x16_bf16 %0, %1, %2, %0\n\ts_nop 7"
        : "+v"(d) : "v"(a), "v"(b));
    return d;
#endif
}

// ---------------- kernel 1: qk = x @ W_down + b_down (fp32, exact) ----------------
__global__ __launch_bounds__(128)
void proj_kernel(const float* __restrict__ x, const float* __restrict__ Wd,
                 const float* __restrict__ bd, float* __restrict__ qk)
{
    __shared__ float xs[512];
    const int row = blockIdx.x;
    const int tid = threadIdx.x;
    const float* xr = x + row * 512;
    #pragma unroll
    for (int e = 0; e < 4; e++) xs[tid + 128 * e] = xr[tid + 128 * e];
    __syncthreads();
    float a0 = 0.f, a1 = 0.f, a2 = 0.f, a3 = 0.f;
    const float* wp = Wd + tid;
    #pragma unroll 4
    for (int e = 0; e < 512; e += 4) {
        a0 = fmaf(xs[e],     wp[(e)     * 128], a0);
        a1 = fmaf(xs[e + 1], wp[(e + 1) * 128], a1);
        a2 = fmaf(xs[e + 2], wp[(e + 2) * 128], a2);
        a3 = fmaf(xs[e + 3], wp[(e + 3) * 128], a3);
    }
    qk[row * 128 + tid] = bd[tid] + ((a0 + a1) + (a2 + a3));
}

// ---------------- kernel 2: pairwise MLP ----------------
// GEMM1: 16x16x32, A = W1T frag (LDS, swizzled), B = pw frag (registers).
// GEMM2: 16x16x16, A = W2 packed frag (LDS), B = silu(acc1) IN REGISTERS.
// LDS 58240 B (static) -> 2 blocks/CU; __launch_bounds__(512,4) -> 4 waves/SIMD.
// Swizzle: byte_in_row ^= (row&7)<<4 (16B granule).

#define LDS_W2P  28672
#define LDS_B1   57344
#define LDS_B2   57792
#define LDS_TOT  58240

__global__ __launch_bounds__(512, 4)
void pair_mlp_kernel(const float* __restrict__ qk,
                     const float* __restrict__ W1, const float* __restrict__ b1,
                     const float* __restrict__ W2, const float* __restrict__ b2,
                     float* __restrict__ dist, float* __restrict__ ang)
{
    __shared__ char smem[LDS_TOT];
    const int tid  = threadIdx.x;
    const int w    = tid >> 6;        // wave 0..7
    const int lane = tid & 63;
    const int l16  = lane & 15;
    const int g    = lane >> 4;       // 0..3
    const int swz  = (l16 & 7) << 4;

    // ---- zero LDS (zero-pads W rows/cols >=100 and bias pads) ----
    for (int idx = tid; idx < LDS_TOT / 4; idx += 512)
        ((float*)smem)[idx] = 0.f;
    __syncthreads();

    // ---- stage W1T[n][k] = W1[k][n], swizzled ----
    for (int idx = tid; idx < 100 * 128; idx += 512) {
        int n = idx >> 7, k = idx & 127;
        int byte = n * 256 + ((2 * k) ^ ((n & 7) << 4));
        *(__bf16*)(smem + byte) = (__bf16)W1[k * DHID + n];
    }
    // ---- stage W2 packed: row n, byte = p*64 + g*16 + half*8 + 2*j  (k = (2p+half)*16+g*4+j) ----
    for (int idx = tid; idx < 100 * 100; idx += 512) {
        int n = idx / 100, k = idx % 100;
        int ks = k >> 4, p = ks >> 1, half = ks & 1, gg = (k >> 2) & 3, j = k & 3;
        int bin = p * 64 + gg * 16 + half * 8 + 2 * j;
        int byte = LDS_W2P + n * 256 + (bin ^ ((n & 7) << 4));
        *(__bf16*)(smem + byte) = (__bf16)W2[k * DHID + n];
    }
    // ---- biases in LDS (frees 56 VGPRs vs register-resident) ----
    if (tid < DHID) {
        ((float*)(smem + LDS_B1))[tid] = b1[tid];
        ((float*)(smem + LDS_B2))[tid] = b2[tid];
    }
    __syncthreads();

    const int bia = (g * 4) * 4;      // byte offset base of this lane's bias quad
    const int TILES = NBATCH * (NSEQ / 8) * (NSEQ / 32);  // 2048

    for (int t = blockIdx.x; t < TILES; t += gridDim.x) {
        int tmp = t;
        const int jb = tmp & 15;  tmp >>= 4;
        const int ib = tmp & 63;  tmp >>= 6;
        const int bi = tmp;
        const int i  = ib * 8 + w;
        const int j0 = jb * 32;

        // ---- q for this wave's i ----
        const float* qrow = qk + (size_t)(bi * NSEQ + i) * 128;
        f32x4 qa0 = *(const f32x4*)(qrow + g * 8);
        f32x4 qa1 = *(const f32x4*)(qrow + g * 8 + 4);
        f32x4 qb0 = *(const f32x4*)(qrow + 32 + g * 8);
        f32x4 qb1 = *(const f32x4*)(qrow + 32 + g * 8 + 4);

        // ---- pw fragments in registers ----
        bf16x8 af[2][4];
        #pragma unroll
        for (int s = 0; s < 2; s++) {
            const float* krow = qk + (size_t)(bi * NSEQ + j0 + s * 16 + l16) * 128 + 64;
            f32x4 ka0 = *(const f32x4*)(krow + g * 8);
            f32x4 ka1 = *(const f32x4*)(krow + g * 8 + 4);
            f32x4 kb0 = *(const f32x4*)(krow + 32 + g * 8);
            f32x4 kb1 = *(const f32x4*)(krow + 32 + g * 8 + 4);
            #pragma unroll
            for (int j = 0; j < 4; j++) {
                af[s][0][j]     = (__bf16)(qa0[j] * ka0[j]);
                af[s][0][j + 4] = (__bf16)(qa1[j] * ka1[j]);
                af[s][1][j]     = (__bf16)(qb0[j] * kb0[j]);
                af[s][1][j + 4] = (__bf16)(qb1[j] * kb1[j]);
                af[s][2][j]     = (__bf16)(ka0[j] - qa0[j]);
                af[s][2][j + 4] = (__bf16)(ka1[j] - qa1[j]);
                af[s][3][j]     = (__bf16)(kb0[j] - qb0[j]);
                af[s][3][j + 4] = (__bf16)(kb1[j] - qb1[j]);
            }
        }

        // ---- GEMM1 (16x16x32): acc1[s][nt] over channel tiles nt ----
        f32x4 acc1[2][7];
        #pragma unroll
        for (int nt = 0; nt < 7; nt++) {
            f32x4 bv = *(const f32x4*)(smem + LDS_B1 + nt * 64 + bia);
            acc1[0][nt] = bv; acc1[1][nt] = bv;
        }
        #pragma unroll
        for (int nt = 0; nt < 7; nt++) {
            const int rbase = (nt * 16 + l16) * 256;
            #pragma unroll
            for (int ks = 0; ks < 4; ks++) {
                bf16x8 wf = *(const bf16x8*)(smem + rbase + ((64 * ks + 16 * g) ^ swz));
                acc1[0][nt] = __builtin_amdgcn_mfma_f32_16x16x32_bf16(wf, af[0][ks], acc1[0][nt], 0, 0, 0);
                acc1[1][nt] = __builtin_amdgcn_mfma_f32_16x16x32_bf16(wf, af[1][ks], acc1[1][nt], 0, 0, 0);
            }
        }

        // ---- silu -> bf16 fragments IN REGISTERS (channels 100..111 are exactly 0
        //      already: zero W1T pad rows + zero bias pad -> silu(0)=0) ----
        bf16x4 hf[2][7];
        #pragma unroll
        for (int s = 0; s < 2; s++)
            #pragma unroll
            for (int nt = 0; nt < 7; nt++)
                #pragma unroll
                for (int r = 0; r < 4; r++) {
                    float z = acc1[s][nt][r];
                    hf[s][nt][r] = (__bf16)(z * __builtin_amdgcn_rcpf(1.f + __expf(-z)));
                }

        // ---- GEMM2 (16x16x16): A = W2 packed frag, B = hf (register-direct) ----
        f32x4 acc2[2][7];
        #pragma unroll
        for (int nt = 0; nt < 7; nt++) {
            f32x4 bv = *(const f32x4*)(smem + LDS_B2 + nt * 64 + bia);
            acc2[0][nt] = bv; acc2[1][nt] = bv;
        }
        #pragma unroll
        for (int nt = 0; nt < 7; nt++) {
            const char* rbase = smem + LDS_W2P + (nt * 16 + l16) * 256;
            #pragma unroll
            for (int p = 0; p < 4; p++) {
                bf16x8 wv = *(const bf16x8*)(rbase + ((p * 64 + 16 * g) ^ swz));
                bf16x4 wlo = __builtin_shufflevector(wv, wv, 0, 1, 2, 3);
                bf16x4 whi = __builtin_shufflevector(wv, wv, 4, 5, 6, 7);
                acc2[0][nt] = mfma16(wlo, hf[0][2 * p], acc2[0][nt]);
                acc2[1][nt] = mfma16(wlo, hf[1][2 * p], acc2[1][nt]);
                if (p < 3) {
                    acc2[0][nt] = mfma16(whi, hf[0][2 * p + 1], acc2[0][nt]);
                    acc2[1][nt] = mfma16(whi, hf[1][2 * p + 1], acc2[1][nt]);
                }
            }
        }

        // ---- coalesced dwordx4 stores ----
        const size_t rowbase = (size_t)(bi * NSEQ + i) * NSEQ + j0;
        #pragma unroll
        for (int s = 0; s < 2; s++) {
            size_t prow = rowbase + s * 16 + l16;
            float* dp = dist + prow * 64;
            float* ap = ang  + prow * 36;
            #pragma unroll
            for (int nt = 0; nt < 4; nt++)
                *(f32x4*)(dp + nt * 16 + g * 4) = acc2[s][nt];
            *(f32x4*)(ap + g * 4)      = acc2[s][4];
            *(f32x4*)(ap + 16 + g * 4) = acc2[s][5];
            if (g == 0) *(f32x4*)(ap + 32) = acc2[s][6];
        }
    }
}

extern "C" void kernel_launch(void* const* d_in, const int* in_sizes, int n_in,
                              void* d_out, int out_size, void* d_ws, size_t ws_size,
                              hipStream_t stream) {
    const float* x  = (const float*)d_in[0];
    const float* Wd = (const float*)d_in[1];
    const float* bd = (const float*)d_in[2];
    const float* W1 = (const float*)d_in[3];
    const float* b1 = (const float*)d_in[4];
    const float* W2 = (const float*)d_in[5];
    const float* b2 = (const float*)d_in[6];

    float* dist = (float*)d_out;                                   // 2*512*512*64
    float* ang  = dist + (size_t)NBATCH * NSEQ * NSEQ * 64;        // 2*512*512*36
    float* qk   = (float*)d_ws;                                    // 1024*128 fp32

    proj_kernel<<<NBATCH * NSEQ, 128, 0, stream>>>(x, Wd, bd, qk);
    pair_mlp_kernel<<<512, 512, 0, stream>>>(qk, W1, b1, W2, b2, dist, ang);
}

// Round 9
// 370.054 us; speedup vs baseline: 1.4564x; 1.4564x over previous
//
#include <hip/hip_runtime.h>
#include <hip/hip_bf16.h>
#include <cstdint>

#define NBATCH 2
#define NSEQ   512
#define DHID   100

typedef __bf16 bf16x8 __attribute__((ext_vector_type(8)));
typedef __bf16 bf16x4 __attribute__((ext_vector_type(4)));
typedef float  f32x4  __attribute__((ext_vector_type(4)));
typedef short  short4v __attribute__((ext_vector_type(4)));

// 16x16x16 bf16 MFMA: B-frag layout (lane g,l16 -> B[g*4+j][l16]) matches the
// 16x16 C/D layout, so GEMM2's h operand comes straight from GEMM1's accumulator.
// (Correctness of this operand path validated in round 4: absmax 0.0039.)
static __device__ __forceinline__ f32x4 mfma16(bf16x4 a, bf16x4 b, f32x4 c) {
#if __has_builtin(__builtin_amdgcn_mfma_f32_16x16x16bf16_1k)
    return __builtin_amdgcn_mfma_f32_16x16x16bf16_1k(
        __builtin_bit_cast(short4v, a), __builtin_bit_cast(short4v, b), c, 0, 0, 0);
#else
    f32x4 d = c;
    asm("v_mfma_f32_16x16x16_bf16 %0, %1, %2, %0\n\ts_nop 7"
        : "+v"(d) : "v"(a), "v"(b));
    return d;
#endif
}

// ---------------- kernel 1: qk = x @ W_down + b_down (fp32, exact) ----------------
__global__ __launch_bounds__(128)
void proj_kernel(const float* __restrict__ x, const float* __restrict__ Wd,
                 const float* __restrict__ bd, float* __restrict__ qk)
{
    __shared__ float xs[512];
    const int row = blockIdx.x;
    const int tid = threadIdx.x;
    const float* xr = x + row * 512;
    #pragma unroll
    for (int e = 0; e < 4; e++) xs[tid + 128 * e] = xr[tid + 128 * e];
    __syncthreads();
    float a0 = 0.f, a1 = 0.f, a2 = 0.f, a3 = 0.f;
    const float* wp = Wd + tid;
    #pragma unroll 4
    for (int e = 0; e < 512; e += 4) {
        a0 = fmaf(xs[e],     wp[(e)     * 128], a0);
        a1 = fmaf(xs[e + 1], wp[(e + 1) * 128], a1);
        a2 = fmaf(xs[e + 2], wp[(e + 2) * 128], a2);
        a3 = fmaf(xs[e + 3], wp[(e + 3) * 128], a3);
    }
    qk[row * 128 + tid] = bd[tid] + ((a0 + a1) + (a2 + a3));
}

// ---------------- kernel 2: pairwise MLP ----------------
// GEMM1: 16x16x32, A = W1T frag (LDS, swizzled), B = pw frag (registers).
// GEMM2: 16x16x16, A = W2 packed frag (LDS), B = silu(acc1) IN REGISTERS.
// s-subtiles processed SEQUENTIALLY (unroll 1) to keep peak live VGPR ~90:
//   pass: af(16) + acc1(28) -> hf(14) + acc2(28), q(16) live across.
// LDS 58240 B static; launch_bounds(512,2) (the empirically-safe setting;
// round 4's (512,4) forced a 64-VGPR cap -> 540 MB scratch spill traffic).
// Swizzle: byte_in_row ^= (row&7)<<4 (16B granule).

#define LDS_W2P  28672
#define LDS_B1   57344
#define LDS_B2   57792
#define LDS_TOT  58240

__global__ __launch_bounds__(512, 2)
void pair_mlp_kernel(const float* __restrict__ qk,
                     const float* __restrict__ W1, const float* __restrict__ b1,
                     const float* __restrict__ W2, const float* __restrict__ b2,
                     float* __restrict__ dist, float* __restrict__ ang)
{
    __shared__ char smem[LDS_TOT];
    const int tid  = threadIdx.x;
    const int w    = tid >> 6;        // wave 0..7
    const int lane = tid & 63;
    const int l16  = lane & 15;
    const int g    = lane >> 4;       // 0..3
    const int swz  = (l16 & 7) << 4;

    // ---- zero LDS (zero-pads W rows/cols >=100 and bias pads) ----
    for (int idx = tid; idx < LDS_TOT / 4; idx += 512)
        ((float*)smem)[idx] = 0.f;
    __syncthreads();

    // ---- stage W1T[n][k] = W1[k][n], swizzled ----
    for (int idx = tid; idx < 100 * 128; idx += 512) {
        int n = idx >> 7, k = idx & 127;
        int byte = n * 256 + ((2 * k) ^ ((n & 7) << 4));
        *(__bf16*)(smem + byte) = (__bf16)W1[k * DHID + n];
    }
    // ---- stage W2 packed: row n, byte = p*64 + g*16 + half*8 + 2*j  (k = (2p+half)*16+g*4+j) ----
    for (int idx = tid; idx < 100 * 100; idx += 512) {
        int n = idx / 100, k = idx % 100;
        int ks = k >> 4, p = ks >> 1, half = ks & 1, gg = (k >> 2) & 3, j = k & 3;
        int bin = p * 64 + gg * 16 + half * 8 + 2 * j;
        int byte = LDS_W2P + n * 256 + (bin ^ ((n & 7) << 4));
        *(__bf16*)(smem + byte) = (__bf16)W2[k * DHID + n];
    }
    // ---- biases in LDS ----
    if (tid < DHID) {
        ((float*)(smem + LDS_B1))[tid] = b1[tid];
        ((float*)(smem + LDS_B2))[tid] = b2[tid];
    }
    __syncthreads();

    const int bia = g * 16;           // byte offset of this lane's bias quad within an nt-tile
    const int TILES = NBATCH * (NSEQ / 8) * (NSEQ / 32);  // 2048

    for (int t = blockIdx.x; t < TILES; t += gridDim.x) {
        int tmp = t;
        const int jb = tmp & 15;  tmp >>= 4;
        const int ib = tmp & 63;  tmp >>= 6;
        const int bi = tmp;
        const int i  = ib * 8 + w;
        const int j0 = jb * 32;

        // ---- q for this wave's i (live across both s passes) ----
        const float* qrow = qk + (size_t)(bi * NSEQ + i) * 128;
        f32x4 qa0 = *(const f32x4*)(qrow + g * 8);
        f32x4 qa1 = *(const f32x4*)(qrow + g * 8 + 4);
        f32x4 qb0 = *(const f32x4*)(qrow + 32 + g * 8);
        f32x4 qb1 = *(const f32x4*)(qrow + 32 + g * 8 + 4);

        const size_t rowbase = (size_t)(bi * NSEQ + i) * NSEQ + j0;

        #pragma unroll 1
        for (int s = 0; s < 2; s++) {
            // ---- k row for this pass ----
            const float* krow = qk + (size_t)(bi * NSEQ + j0 + s * 16 + l16) * 128 + 64;
            f32x4 ka0 = *(const f32x4*)(krow + g * 8);
            f32x4 ka1 = *(const f32x4*)(krow + g * 8 + 4);
            f32x4 kb0 = *(const f32x4*)(krow + 32 + g * 8);
            f32x4 kb1 = *(const f32x4*)(krow + 32 + g * 8 + 4);

            // ---- pw fragments in registers ----
            bf16x8 af[4];
            #pragma unroll
            for (int j = 0; j < 4; j++) {
                af[0][j]     = (__bf16)(qa0[j] * ka0[j]);
                af[0][j + 4] = (__bf16)(qa1[j] * ka1[j]);
                af[1][j]     = (__bf16)(qb0[j] * kb0[j]);
                af[1][j + 4] = (__bf16)(qb1[j] * kb1[j]);
                af[2][j]     = (__bf16)(ka0[j] - qa0[j]);
                af[2][j + 4] = (__bf16)(ka1[j] - qa1[j]);
                af[3][j]     = (__bf16)(kb0[j] - qb0[j]);
                af[3][j + 4] = (__bf16)(kb1[j] - qb1[j]);
            }

            // ---- GEMM1 (16x16x32): acc1[nt] over channel tiles ----
            f32x4 acc1[7];
            #pragma unroll
            for (int nt = 0; nt < 7; nt++)
                acc1[nt] = *(const f32x4*)(smem + LDS_B1 + nt * 64 + bia);
            #pragma unroll
            for (int nt = 0; nt < 7; nt++) {
                const int rbase = (nt * 16 + l16) * 256;
                #pragma unroll
                for (int ks = 0; ks < 4; ks++) {
                    bf16x8 wf = *(const bf16x8*)(smem + rbase + ((64 * ks + 16 * g) ^ swz));
                    acc1[nt] = __builtin_amdgcn_mfma_f32_16x16x32_bf16(wf, af[ks], acc1[nt], 0, 0, 0);
                }
            }

            // ---- silu -> bf16 fragments IN REGISTERS (channels 100..111 exactly 0:
            //      zero W1T pad rows + zero bias pad -> silu(0)=0) ----
            bf16x4 hf[7];
            #pragma unroll
            for (int nt = 0; nt < 7; nt++)
                #pragma unroll
                for (int r = 0; r < 4; r++) {
                    float z = acc1[nt][r];
                    hf[nt][r] = (__bf16)(z * __builtin_amdgcn_rcpf(1.f + __expf(-z)));
                }

            // ---- GEMM2 (16x16x16): A = W2 packed frag, B = hf (register-direct) ----
            f32x4 acc2[7];
            #pragma unroll
            for (int nt = 0; nt < 7; nt++)
                acc2[nt] = *(const f32x4*)(smem + LDS_B2 + nt * 64 + bia);
            #pragma unroll
            for (int nt = 0; nt < 7; nt++) {
                const char* rbase = smem + LDS_W2P + (nt * 16 + l16) * 256;
                #pragma unroll
                for (int p = 0; p < 4; p++) {
                    bf16x8 wv = *(const bf16x8*)(rbase + ((p * 64 + 16 * g) ^ swz));
                    bf16x4 wlo = __builtin_shufflevector(wv, wv, 0, 1, 2, 3);
                    bf16x4 whi = __builtin_shufflevector(wv, wv, 4, 5, 6, 7);
                    acc2[nt] = mfma16(wlo, hf[2 * p], acc2[nt]);
                    if (p < 3)
                        acc2[nt] = mfma16(whi, hf[2 * p + 1], acc2[nt]);
                }
            }

            // ---- coalesced dwordx4 stores ----
            size_t prow = rowbase + s * 16 + l16;
            float* dp = dist + prow * 64;
            float* ap = ang  + prow * 36;
            #pragma unroll
            for (int nt = 0; nt < 4; nt++)
                *(f32x4*)(dp + nt * 16 + g * 4) = acc2[nt];
            *(f32x4*)(ap + g * 4)      = acc2[4];
            *(f32x4*)(ap + 16 + g * 4) = acc2[5];
            if (g == 0) *(f32x4*)(ap + 32) = acc2[6];
        }
    }
}

extern "C" void kernel_launch(void* const* d_in, const int* in_sizes, int n_in,
                              void* d_out, int out_size, void* d_ws, size_t ws_size,
                              hipStream_t stream) {
    const float* x  = (const float*)d_in[0];
    const float* Wd = (const float*)d_in[1];
    const float* bd = (const float*)d_in[2];
    const float* W1 = (const float*)d_in[3];
    const float* b1 = (const float*)d_in[4];
    const float* W2 = (const float*)d_in[5];
    const float* b2 = (const float*)d_in[6];

    float* dist = (float*)d_out;                                   // 2*512*512*64
    float* ang  = dist + (size_t)NBATCH * NSEQ * NSEQ * 64;        // 2*512*512*36
    float* qk   = (float*)d_ws;                                    // 1024*128 fp32

    proj_kernel<<<NBATCH * NSEQ, 128, 0, stream>>>(x, Wd, bd, qk);
    pair_mlp_kernel<<<512, 512, 0, stream>>>(qk, W1, b1, W2, b2, dist, ang);
}